// Round 1
// baseline (258.321 us; speedup 1.0000x reference)
//
#include <hip/hip_runtime.h>

// ---------------------------------------------------------------------------
// MultiHeadAttention forward, MI355X/gfx950.
// Pipeline:
//   1. pack_bf16: fp32 -> bf16 copies of query/key/value and wq/wk/wv/wo
//   2. gemm_nt<0>: qp = (query @ wq^T + bq) * 0.125   [4096][1024] bf16
//      gemm_nt<0>: kp = key   @ wk^T + bk             [4096][1024] bf16
//      gemm_nt<1>: vt = value @ wv^T + bv, stored TRANSPOSED [BH=32][64][2048]
//   3. attn_fwd: flash attention, Q/K/V frags loaded direct global->reg
//      (vt transposed layout makes PV B-frags contiguous), P via per-wave LDS
//   4. gemm_nt<2>: out = attnout @ wo^T + bo, fp32 -> d_out
// Workspace: 3*8MB(x) + 4*2MB(w) + 3*8MB(qp/kp/vt) + 8MB(op) = 64 MB.
// ---------------------------------------------------------------------------

typedef __attribute__((ext_vector_type(8))) short short8;     // 8 x bf16 frag
typedef __attribute__((ext_vector_type(4))) float f32x4;      // MFMA acc
typedef __attribute__((ext_vector_type(4))) float float4v;
typedef __attribute__((ext_vector_type(4))) unsigned short ushort4v;

typedef __attribute__((address_space(3))) unsigned int lds_uint;
typedef __attribute__((address_space(1))) unsigned int glb_uint;

// async global->LDS, 16B per lane. LDS dest must be wave-uniform; HW writes
// lane i at (base + 16*i). Casts go through integers: generic LDS pointer's
// low 32 bits are the LDS offset on gfx9xx.
__device__ __forceinline__ void gload_lds16(const void* g, void* l) {
    __builtin_amdgcn_global_load_lds((glb_uint*)(unsigned long long)g,
                                     (lds_uint*)(unsigned int)(unsigned long long)l,
                                     16, 0, 0);
}

__device__ __forceinline__ unsigned short f32_bf16(float f) {
    union { float f; unsigned int u; } x; x.f = f;
    unsigned int r = x.u + 0x7fffu + ((x.u >> 16) & 1u);   // RNE
    return (unsigned short)(r >> 16);
}

// ---------------------------------------------------------------------------
__global__ void pack_bf16(const float* __restrict__ in,
                          unsigned short* __restrict__ out, int n4) {
    int i = blockIdx.x * blockDim.x + threadIdx.x;
    if (i < n4) {
        float4v v = ((const float4v*)in)[i];
        ushort4v o;
        o.x = f32_bf16(v.x); o.y = f32_bf16(v.y);
        o.z = f32_bf16(v.z); o.w = f32_bf16(v.w);
        ((ushort4v*)out)[i] = o;
    }
}

// ---------------------------------------------------------------------------
// NT GEMM: C[m][n] = sum_k A[m][k] * Bw[n][k] + bias[n], all K-contiguous.
// BM=BN=128, BK=64, 256 threads (4 waves, 2x2 wave grid, 64x64 per wave),
// mfma_f32_16x16x32_bf16, acc 4x4 frags.
// OM=0: bf16 row-major [M][N]; OM=1: bf16 transposed-V [B][H][64][2048];
// OM=2: fp32 row-major.
template<int OM>
__global__ __launch_bounds__(256, 2) void gemm_nt(
    const unsigned short* __restrict__ A,
    const unsigned short* __restrict__ Bw,
    const float* __restrict__ bias,
    void* __restrict__ C,
    int M, int N, int K, float oscale)
{
    __shared__ unsigned short As[128 * 64];
    __shared__ unsigned short Bs[128 * 64];
    const int tid  = threadIdx.x;
    const int lane = tid & 63, wave = tid >> 6;
    const int l15 = lane & 15, l4 = lane >> 4;
    const int bm = blockIdx.y * 128, bn = blockIdx.x * 128;
    const int wr = wave >> 1, wc = wave & 1;

    f32x4 acc[4][4];
    #pragma unroll
    for (int i = 0; i < 4; ++i)
        #pragma unroll
        for (int j = 0; j < 4; ++j)
            #pragma unroll
            for (int e = 0; e < 4; ++e) acc[i][j][e] = 0.f;

    const int srow = lane >> 3;          // 0..7 within 8-row chunk
    const int scol = (lane & 7) * 8;     // 0,8,..,56

    for (int k0 = 0; k0 < K; k0 += 64) {
        __syncthreads();                 // all waves done reading prev tile
        #pragma unroll
        for (int i = 0; i < 4; ++i) {
            int c = wave * 4 + i;        // chunk 0..15, 1KB each
            int row = c * 8 + srow;
            gload_lds16(A  + (size_t)(bm + row) * K + k0 + scol, &As[c * 512]);
            gload_lds16(Bw + (size_t)(bn + row) * K + k0 + scol, &Bs[c * 512]);
        }
        __syncthreads();                 // drains vmcnt -> LDS visible
        #pragma unroll
        for (int kk = 0; kk < 2; ++kk) {
            short8 af[4], bf[4];
            const int ko = kk * 32 + l4 * 8;
            #pragma unroll
            for (int i = 0; i < 4; ++i)
                af[i] = *(const short8*)&As[(wr * 64 + i * 16 + l15) * 64 + ko];
            #pragma unroll
            for (int j = 0; j < 4; ++j)
                bf[j] = *(const short8*)&Bs[(wc * 64 + j * 16 + l15) * 64 + ko];
            #pragma unroll
            for (int i = 0; i < 4; ++i)
                #pragma unroll
                for (int j = 0; j < 4; ++j)
                    acc[i][j] = __builtin_amdgcn_mfma_f32_16x16x32_bf16(
                        af[i], bf[j], acc[i][j], 0, 0, 0);
        }
    }

    // epilogue: C/D layout col=lane&15, row=(lane>>4)*4+reg (m89-verified)
    #pragma unroll
    for (int j = 0; j < 4; ++j) {
        const int col = bn + wc * 64 + j * 16 + l15;
        const float bj = bias[col];
        #pragma unroll
        for (int i = 0; i < 4; ++i) {
            const int row0 = bm + wr * 64 + i * 16 + l4 * 4;
            #pragma unroll
            for (int r = 0; r < 4; ++r) {
                const int row = row0 + r;
                const float v = (acc[i][j][r] + bj) * oscale;
                if (OM == 2) {
                    ((float*)C)[(size_t)row * N + col] = v;
                } else if (OM == 0) {
                    ((unsigned short*)C)[(size_t)row * N + col] = f32_bf16(v);
                } else {
                    // V transposed store: [b][h][hd][t], T=2048
                    const int b = row >> 11, t = row & 2047;
                    ((unsigned short*)C)[(((size_t)((b << 4) + (col >> 6)) * 64
                                           + (col & 63)) << 11) + t] = f32_bf16(v);
                }
            }
        }
    }
}

// ---------------------------------------------------------------------------
// Flash attention. grid(16, 32): x = q-tile (128 rows), y = bh.
// 4 waves/block, 32 q-rows per wave. Q/K layout [B][T][H*64] (K-contiguous),
// V layout [BH][64][T] (pre-transposed so PV B-frags are contiguous).
// S acc: row=q=(l>>4)*4+r, col=kv=lane&15 (+16*nfrag). Online softmax in
// fp32; P round-trips through per-wave LDS (pad 136 -> 2-way banks = free).
__global__ __launch_bounds__(256, 2) void attn_fwd(
    const unsigned short* __restrict__ qp,
    const unsigned short* __restrict__ kp,
    const unsigned short* __restrict__ vt,
    unsigned short* __restrict__ op)
{
    __shared__ unsigned short P[4][32][136];
    const int tid = threadIdx.x;
    const int lane = tid & 63, wave = tid >> 6;
    const int l15 = lane & 15, l4 = lane >> 4;
    const int bh = blockIdx.y;
    const int b = bh >> 4, h = bh & 15;
    const int q0 = blockIdx.x * 128 + wave * 32;

    const size_t xbase = (size_t)b * 2048 * 1024 + h * 64;   // into qp/kp
    const size_t vbase = (size_t)bh * 64 * 2048;             // into vt

    // Q fragments, held in registers for the whole kernel
    short8 aq[2][2];
    #pragma unroll
    for (int mi = 0; mi < 2; ++mi)
        #pragma unroll
        for (int kk = 0; kk < 2; ++kk)
            aq[mi][kk] = *(const short8*)&qp[xbase
                + (size_t)(q0 + mi * 16 + l15) * 1024 + kk * 32 + l4 * 8];

    f32x4 acc_o[2][4];
    #pragma unroll
    for (int mi = 0; mi < 2; ++mi)
        #pragma unroll
        for (int dj = 0; dj < 4; ++dj)
            #pragma unroll
            for (int e = 0; e < 4; ++e) acc_o[mi][dj][e] = 0.f;

    float m_run[2][4], l_run[2][4];
    #pragma unroll
    for (int mi = 0; mi < 2; ++mi)
        #pragma unroll
        for (int r = 0; r < 4; ++r) { m_run[mi][r] = -1e30f; l_run[mi][r] = 0.f; }

    for (int kv0 = 0; kv0 < 2048; kv0 += 128) {
        // ---- S = Q K^T (scale already folded into Q) ----
        f32x4 s[2][8];
        #pragma unroll
        for (int mi = 0; mi < 2; ++mi)
            #pragma unroll
            for (int j = 0; j < 8; ++j)
                #pragma unroll
                for (int e = 0; e < 4; ++e) s[mi][j][e] = 0.f;

        #pragma unroll
        for (int kk = 0; kk < 2; ++kk) {
            short8 bk[8];
            #pragma unroll
            for (int j = 0; j < 8; ++j)
                bk[j] = *(const short8*)&kp[xbase
                    + (size_t)(kv0 + j * 16 + l15) * 1024 + kk * 32 + l4 * 8];
            #pragma unroll
            for (int mi = 0; mi < 2; ++mi)
                #pragma unroll
                for (int j = 0; j < 8; ++j)
                    s[mi][j] = __builtin_amdgcn_mfma_f32_16x16x32_bf16(
                        aq[mi][kk], bk[j], s[mi][j], 0, 0, 0);
        }

        // ---- online softmax per q-row ----
        #pragma unroll
        for (int mi = 0; mi < 2; ++mi) {
            #pragma unroll
            for (int r = 0; r < 4; ++r) {
                float mx = s[mi][0][r];
                #pragma unroll
                for (int j = 1; j < 8; ++j) mx = fmaxf(mx, s[mi][j][r]);
                #pragma unroll
                for (int o = 1; o < 16; o <<= 1)
                    mx = fmaxf(mx, __shfl_xor(mx, o, 64));
                const float mold = m_run[mi][r];
                const float mnew = fmaxf(mold, mx);
                const float corr = __expf(mold - mnew);
                float lsum = 0.f;
                #pragma unroll
                for (int j = 0; j < 8; ++j) {
                    const float p = __expf(s[mi][j][r] - mnew);
                    s[mi][j][r] = p;
                    lsum += p;
                }
                #pragma unroll
                for (int o = 1; o < 16; o <<= 1)
                    lsum += __shfl_xor(lsum, o, 64);
                m_run[mi][r] = mnew;
                l_run[mi][r] = l_run[mi][r] * corr + lsum;
                #pragma unroll
                for (int dj = 0; dj < 4; ++dj) acc_o[mi][dj][r] *= corr;
            }
        }

        // ---- P (bf16) to per-wave LDS: acc layout -> A-frag layout ----
        #pragma unroll
        for (int mi = 0; mi < 2; ++mi)
            #pragma unroll
            for (int j = 0; j < 8; ++j)
                #pragma unroll
                for (int r = 0; r < 4; ++r)
                    P[wave][mi * 16 + l4 * 4 + r][j * 16 + l15] =
                        f32_bf16(s[mi][j][r]);

        // ---- O += P V ----
        #pragma unroll
        for (int kvc = 0; kvc < 4; ++kvc) {
            short8 pa[2], bv[4];
            #pragma unroll
            for (int mi = 0; mi < 2; ++mi)
                pa[mi] = *(const short8*)&P[wave][mi * 16 + l15][kvc * 32 + l4 * 8];
            #pragma unroll
            for (int dj = 0; dj < 4; ++dj)
                bv[dj] = *(const short8*)&vt[vbase
                    + (size_t)(dj * 16 + l15) * 2048 + kv0 + kvc * 32 + l4 * 8];
            #pragma unroll
            for (int mi = 0; mi < 2; ++mi)
                #pragma unroll
                for (int dj = 0; dj < 4; ++dj)
                    acc_o[mi][dj] = __builtin_amdgcn_mfma_f32_16x16x32_bf16(
                        pa[mi], bv[dj], acc_o[mi][dj], 0, 0, 0);
        }
    }

    // ---- epilogue: normalize, write [b][t][h*64+d] bf16 ----
    #pragma unroll
    for (int mi = 0; mi < 2; ++mi)
        #pragma unroll
        for (int dj = 0; dj < 4; ++dj)
            #pragma unroll
            for (int r = 0; r < 4; ++r) {
                const int t = q0 + mi * 16 + l4 * 4 + r;
                const float v = acc_o[mi][dj][r] / l_run[mi][r];
                op[((size_t)(b * 2048 + t)) * 1024 + h * 64 + dj * 16 + l15] =
                    f32_bf16(v);
            }
}

// ---------------------------------------------------------------------------
extern "C" void kernel_launch(void* const* d_in, const int* in_sizes, int n_in,
                              void* d_out, int out_size, void* d_ws, size_t ws_size,
                              hipStream_t stream)
{
    const float* q  = (const float*)d_in[0];
    const float* k  = (const float*)d_in[1];
    const float* v  = (const float*)d_in[2];
    const float* wq = (const float*)d_in[3];
    const float* bq = (const float*)d_in[4];
    const float* wk = (const float*)d_in[5];
    const float* bk = (const float*)d_in[6];
    const float* wv = (const float*)d_in[7];
    const float* bv = (const float*)d_in[8];
    const float* wo = (const float*)d_in[9];
    const float* bo = (const float*)d_in[10];
    float* out = (float*)d_out;

    const int M = 4096, N = 1024, K = 1024;     // M = B*T
    unsigned char* ws = (unsigned char*)d_ws;
    const size_t SX = (size_t)M * K * 2;        // 8 MB
    const size_t SW = (size_t)N * K * 2;        // 2 MB
    unsigned short* xq  = (unsigned short*)(ws);
    unsigned short* xk  = (unsigned short*)(ws + SX);
    unsigned short* xv  = (unsigned short*)(ws + 2 * SX);
    unsigned short* wqb = (unsigned short*)(ws + 3 * SX);
    unsigned short* wkb = (unsigned short*)(ws + 3 * SX + SW);
    unsigned short* wvb = (unsigned short*)(ws + 3 * SX + 2 * SW);
    unsigned short* wob = (unsigned short*)(ws + 3 * SX + 3 * SW);
    unsigned short* qp  = (unsigned short*)(ws + 3 * SX + 4 * SW);
    unsigned short* kp  = qp + (size_t)M * N;
    unsigned short* vt  = kp + (size_t)M * N;
    unsigned short* opb = vt + (size_t)M * N;

    const int nX4 = M * K / 4, nW4 = N * K / 4;
    pack_bf16<<<nX4 / 256, 256, 0, stream>>>(q,  xq,  nX4);
    pack_bf16<<<nX4 / 256, 256, 0, stream>>>(k,  xk,  nX4);
    pack_bf16<<<nX4 / 256, 256, 0, stream>>>(v,  xv,  nX4);
    pack_bf16<<<nW4 / 256, 256, 0, stream>>>(wq, wqb, nW4);
    pack_bf16<<<nW4 / 256, 256, 0, stream>>>(wk, wkb, nW4);
    pack_bf16<<<nW4 / 256, 256, 0, stream>>>(wv, wvb, nW4);
    pack_bf16<<<nW4 / 256, 256, 0, stream>>>(wo, wob, nW4);

    dim3 gg(N / 128, M / 128);   // (8, 32)
    // scale = HEAD_DIM^-0.5 = 0.125 folded into Q projection (pow2 => exact)
    gemm_nt<0><<<gg, 256, 0, stream>>>(xq, wqb, bq, qp,  M, N, K, 0.125f);
    gemm_nt<0><<<gg, 256, 0, stream>>>(xk, wkb, bk, kp,  M, N, K, 1.0f);
    gemm_nt<1><<<gg, 256, 0, stream>>>(xv, wvb, bv, vt,  M, N, K, 1.0f);

    attn_fwd<<<dim3(16, 32), 256, 0, stream>>>(qp, kp, vt, opb);

    gemm_nt<2><<<gg, 256, 0, stream>>>(opb, wob, bo, out, M, N, K, 1.0f);
}

// Round 2
// 220.012 us; speedup vs baseline: 1.1741x; 1.1741x over previous
//
#include <hip/hip_runtime.h>
#include <math.h>

// ---------------------------------------------------------------------------
// MultiHeadAttention forward, MI355X/gfx950.  Round 2.
//   pack3/pack4: fp32 -> bf16 (fused, 2 launches)
//   gemm_qkv (z=0,1,2): q' = (x@wq^T+bq)*0.125*log2e ; k' ; v -> vt [BH][64][T]
//   attn_fwd: swapped QK^T (S^T) + swapped PV (O^T) -> in-lane softmax (exp2),
//             cvt_pk bf16 P, LDS b64 writes / b128 reads, V prefetch
//   gemm_nt<2>: out = attnout @ wo^T + bo (fp32)
// ---------------------------------------------------------------------------

typedef __attribute__((ext_vector_type(8))) short short8;     // 8 x bf16 frag
typedef __attribute__((ext_vector_type(4))) float f32x4;      // MFMA acc
typedef __attribute__((ext_vector_type(4))) float float4v;
typedef __attribute__((ext_vector_type(4))) unsigned short ushort4v;
typedef __attribute__((ext_vector_type(2))) unsigned int uint2v;

typedef __attribute__((address_space(3))) unsigned int lds_uint;
typedef __attribute__((address_space(1))) unsigned int glb_uint;

__device__ __forceinline__ void gload_lds16(const void* g, void* l) {
    __builtin_amdgcn_global_load_lds((glb_uint*)(unsigned long long)g,
                                     (lds_uint*)(unsigned int)(unsigned long long)l,
                                     16, 0, 0);
}

__device__ __forceinline__ unsigned short f32_bf16(float f) {
    union { float f; unsigned int u; } x; x.f = f;
    unsigned int r = x.u + 0x7fffu + ((x.u >> 16) & 1u);   // RNE
    return (unsigned short)(r >> 16);
}

// packed f32->bf16: D.b16[0]=bf16(lo), D.b16[1]=bf16(hi)  (T12 recipe)
__device__ __forceinline__ unsigned int cvt_pk_bf16(float lo, float hi) {
    unsigned int r;
    asm("v_cvt_pk_bf16_f32 %0, %1, %2" : "=v"(r) : "v"(lo), "v"(hi));
    return r;
}

// SCALE * log2(e): folded into Q projection so softmax runs in exp2 domain
#define QSCALE 0.18033688011112042f

// ---------------------------------------------------------------------------
__global__ void pack3_bf16(const float* __restrict__ a, const float* __restrict__ b,
                           const float* __restrict__ c,
                           unsigned short* __restrict__ oa, unsigned short* __restrict__ ob,
                           unsigned short* __restrict__ oc, int n4) {
    const int y = blockIdx.y;
    const float* in = (y == 0) ? a : (y == 1) ? b : c;
    unsigned short* out = (y == 0) ? oa : (y == 1) ? ob : oc;
    int i = blockIdx.x * blockDim.x + threadIdx.x;
    if (i < n4) {
        float4v v = ((const float4v*)in)[i];
        ushort4v o;
        o.x = f32_bf16(v.x); o.y = f32_bf16(v.y);
        o.z = f32_bf16(v.z); o.w = f32_bf16(v.w);
        ((ushort4v*)out)[i] = o;
    }
}

__global__ void pack4_bf16(const float* __restrict__ a, const float* __restrict__ b,
                           const float* __restrict__ c, const float* __restrict__ d,
                           unsigned short* __restrict__ oa, unsigned short* __restrict__ ob,
                           unsigned short* __restrict__ oc, unsigned short* __restrict__ od,
                           int n4) {
    const int y = blockIdx.y;
    const float* in = (y == 0) ? a : (y == 1) ? b : (y == 2) ? c : d;
    unsigned short* out = (y == 0) ? oa : (y == 1) ? ob : (y == 2) ? oc : od;
    int i = blockIdx.x * blockDim.x + threadIdx.x;
    if (i < n4) {
        float4v v = ((const float4v*)in)[i];
        ushort4v o;
        o.x = f32_bf16(v.x); o.y = f32_bf16(v.y);
        o.z = f32_bf16(v.z); o.w = f32_bf16(v.w);
        ((ushort4v*)out)[i] = o;
    }
}

// ---------------------------------------------------------------------------
// Batched QKV projection GEMM.  grid (8, 32, 3); z selects {A,W,bias,C,mode}.
// C[m][n] = (sum_k A[m][k]*W[n][k] + bias[n]) * oscale.  M=4096,N=K=1024.
// z=0: Q, scaled by QSCALE, bf16 row-major.  z=1: K, bf16 row-major.
// z=2: V, stored transposed [bh][64][2048].
__global__ __launch_bounds__(256, 2) void gemm_qkv(
    const unsigned short* __restrict__ A0, const unsigned short* __restrict__ A1,
    const unsigned short* __restrict__ A2,
    const unsigned short* __restrict__ W0, const unsigned short* __restrict__ W1,
    const unsigned short* __restrict__ W2,
    const float* __restrict__ bs0, const float* __restrict__ bs1,
    const float* __restrict__ bs2,
    unsigned short* __restrict__ O0, unsigned short* __restrict__ O1,
    unsigned short* __restrict__ O2)
{
    const int z = blockIdx.z;
    const unsigned short* A = (z == 0) ? A0 : (z == 1) ? A1 : A2;
    const unsigned short* W = (z == 0) ? W0 : (z == 1) ? W1 : W2;
    const float* bias        = (z == 0) ? bs0 : (z == 1) ? bs1 : bs2;
    unsigned short* C        = (z == 0) ? O0 : (z == 1) ? O1 : O2;
    const float oscale = (z == 0) ? QSCALE : 1.0f;
    const int N = 1024, K = 1024;

    __shared__ unsigned short As[128 * 64];
    __shared__ unsigned short Bs[128 * 64];
    const int tid  = threadIdx.x;
    const int lane = tid & 63, wave = tid >> 6;
    const int l15 = lane & 15, l4 = lane >> 4;
    const int bm = blockIdx.y * 128, bn = blockIdx.x * 128;
    const int wr = wave >> 1, wc = wave & 1;

    f32x4 acc[4][4];
    #pragma unroll
    for (int i = 0; i < 4; ++i)
        #pragma unroll
        for (int j = 0; j < 4; ++j)
            #pragma unroll
            for (int e = 0; e < 4; ++e) acc[i][j][e] = 0.f;

    const int srow = lane >> 3;
    const int scol = (lane & 7) * 8;

    for (int k0 = 0; k0 < K; k0 += 64) {
        __syncthreads();
        #pragma unroll
        for (int i = 0; i < 4; ++i) {
            int c = wave * 4 + i;
            int row = c * 8 + srow;
            gload_lds16(A + (size_t)(bm + row) * K + k0 + scol, &As[c * 512]);
            gload_lds16(W + (size_t)(bn + row) * K + k0 + scol, &Bs[c * 512]);
        }
        __syncthreads();
        #pragma unroll
        for (int kk = 0; kk < 2; ++kk) {
            short8 af[4], bf[4];
            const int ko = kk * 32 + l4 * 8;
            #pragma unroll
            for (int i = 0; i < 4; ++i)
                af[i] = *(const short8*)&As[(wr * 64 + i * 16 + l15) * 64 + ko];
            #pragma unroll
            for (int j = 0; j < 4; ++j)
                bf[j] = *(const short8*)&Bs[(wc * 64 + j * 16 + l15) * 64 + ko];
            #pragma unroll
            for (int i = 0; i < 4; ++i)
                #pragma unroll
                for (int j = 0; j < 4; ++j)
                    acc[i][j] = __builtin_amdgcn_mfma_f32_16x16x32_bf16(
                        af[i], bf[j], acc[i][j], 0, 0, 0);
        }
    }

    #pragma unroll
    for (int j = 0; j < 4; ++j) {
        const int col = bn + wc * 64 + j * 16 + l15;
        const float bj = bias[col];
        #pragma unroll
        for (int i = 0; i < 4; ++i) {
            const int row0 = bm + wr * 64 + i * 16 + l4 * 4;
            #pragma unroll
            for (int r = 0; r < 4; ++r) {
                const int row = row0 + r;
                const float v = (acc[i][j][r] + bj) * oscale;
                if (z < 2) {
                    C[(size_t)row * N + col] = f32_bf16(v);
                } else {
                    const int b = row >> 11, t = row & 2047;
                    C[(((size_t)((b << 4) + (col >> 6)) * 64
                        + (col & 63)) << 11) + t] = f32_bf16(v);
                }
            }
        }
    }
}

// ---------------------------------------------------------------------------
// Output-projection GEMM (fp32 out), same structure.
__global__ __launch_bounds__(256, 2) void gemm_out(
    const unsigned short* __restrict__ A,
    const unsigned short* __restrict__ W,
    const float* __restrict__ bias,
    float* __restrict__ C)
{
    const int N = 1024, K = 1024;
    __shared__ unsigned short As[128 * 64];
    __shared__ unsigned short Bs[128 * 64];
    const int tid  = threadIdx.x;
    const int lane = tid & 63, wave = tid >> 6;
    const int l15 = lane & 15, l4 = lane >> 4;
    const int bm = blockIdx.y * 128, bn = blockIdx.x * 128;
    const int wr = wave >> 1, wc = wave & 1;

    f32x4 acc[4][4];
    #pragma unroll
    for (int i = 0; i < 4; ++i)
        #pragma unroll
        for (int j = 0; j < 4; ++j)
            #pragma unroll
            for (int e = 0; e < 4; ++e) acc[i][j][e] = 0.f;

    const int srow = lane >> 3;
    const int scol = (lane & 7) * 8;

    for (int k0 = 0; k0 < K; k0 += 64) {
        __syncthreads();
        #pragma unroll
        for (int i = 0; i < 4; ++i) {
            int c = wave * 4 + i;
            int row = c * 8 + srow;
            gload_lds16(A + (size_t)(bm + row) * K + k0 + scol, &As[c * 512]);
            gload_lds16(W + (size_t)(bn + row) * K + k0 + scol, &Bs[c * 512]);
        }
        __syncthreads();
        #pragma unroll
        for (int kk = 0; kk < 2; ++kk) {
            short8 af[4], bf[4];
            const int ko = kk * 32 + l4 * 8;
            #pragma unroll
            for (int i = 0; i < 4; ++i)
                af[i] = *(const short8*)&As[(wr * 64 + i * 16 + l15) * 64 + ko];
            #pragma unroll
            for (int j = 0; j < 4; ++j)
                bf[j] = *(const short8*)&Bs[(wc * 64 + j * 16 + l15) * 64 + ko];
            #pragma unroll
            for (int i = 0; i < 4; ++i)
                #pragma unroll
                for (int j = 0; j < 4; ++j)
                    acc[i][j] = __builtin_amdgcn_mfma_f32_16x16x32_bf16(
                        af[i], bf[j], acc[i][j], 0, 0, 0);
        }
    }

    #pragma unroll
    for (int j = 0; j < 4; ++j) {
        const int col = bn + wc * 64 + j * 16 + l15;
        const float bj = bias[col];
        #pragma unroll
        for (int i = 0; i < 4; ++i) {
            const int row0 = bm + wr * 64 + i * 16 + l4 * 4;
            #pragma unroll
            for (int r = 0; r < 4; ++r)
                C[(size_t)(row0 + r) * N + col] = acc[i][j][r] + bj;
        }
    }
}

// ---------------------------------------------------------------------------
// Flash attention, fully swapped.  grid (16, 32): x = q-tile (128), y = bh.
// 4 waves, 32 q-rows/wave.  S^T = mfma(K, Q): per-lane holds a q-row's kv
// values (q = mi*16+l15) -> in-lane softmax (exp2 domain), 2 shfl_xor per
// reduce.  P^T -> LDS via cvt_pk + ds_write_b64; PV swapped: O^T =
// mfma(V^T, P^T) so rescale/div are lane-local.  V frags prefetch under
// softmax.
__global__ __launch_bounds__(256, 2) void attn_fwd(
    const unsigned short* __restrict__ qp,
    const unsigned short* __restrict__ kp,
    const unsigned short* __restrict__ vt,
    unsigned short* __restrict__ op)
{
    __shared__ __align__(16) unsigned short P[4][32][136];  // [wave][q][kv pad]
    const int tid = threadIdx.x;
    const int lane = tid & 63, wave = tid >> 6;
    const int l15 = lane & 15, l4 = lane >> 4;
    const int bh = blockIdx.y;
    const int b = bh >> 4, h = bh & 15;
    const int q0 = blockIdx.x * 128 + wave * 32;

    const size_t xbase = (size_t)b * 2048 * 1024 + h * 64;   // qp/kp
    const size_t vbase = (size_t)bh * 64 * 2048;             // vt

    // Q as B-operand frags: col=q (l15), k=d (kk*32+l4*8+e)
    short8 bq[2][2];
    #pragma unroll
    for (int mi = 0; mi < 2; ++mi)
        #pragma unroll
        for (int kk = 0; kk < 2; ++kk)
            bq[mi][kk] = *(const short8*)&qp[xbase
                + (size_t)(q0 + mi * 16 + l15) * 1024 + kk * 32 + l4 * 8];

    f32x4 acc[2][4];        // O^T: [mi(q-col)][dj]; row=d_local, col=q=l15
    #pragma unroll
    for (int mi = 0; mi < 2; ++mi)
        #pragma unroll
        for (int dj = 0; dj < 4; ++dj)
            #pragma unroll
            for (int e = 0; e < 4; ++e) acc[mi][dj][e] = 0.f;

    float m_run[2] = {-1e30f, -1e30f};      // log2 domain, q = mi*16+l15
    float l_run[2] = {0.f, 0.f};

    const unsigned short* kb = kp + xbase + (size_t)l15 * 1024 + l4 * 8;
    const unsigned short* vb = vt + vbase + (size_t)l15 * 2048 + l4 * 8;

    for (int kv0 = 0; kv0 < 2048; kv0 += 128) {
        // ---- S^T = K Q^T : row=kv_local, col=q ----
        f32x4 st[2][8];     // [mi][j]: kv = j*16 + l4*4 + r ; q = mi*16+l15
        {
            short8 ak[8];
            #pragma unroll
            for (int j = 0; j < 8; ++j)
                ak[j] = *(const short8*)&kb[(size_t)(kv0 + j * 16) * 1024];
            const f32x4 z4 = {0.f, 0.f, 0.f, 0.f};
            #pragma unroll
            for (int mi = 0; mi < 2; ++mi)
                #pragma unroll
                for (int j = 0; j < 8; ++j)
                    st[mi][j] = __builtin_amdgcn_mfma_f32_16x16x32_bf16(
                        ak[j], bq[mi][0], z4, 0, 0, 0);
        }
        {
            short8 ak[8];
            #pragma unroll
            for (int j = 0; j < 8; ++j)
                ak[j] = *(const short8*)&kb[(size_t)(kv0 + j * 16) * 1024 + 32];
            #pragma unroll
            for (int mi = 0; mi < 2; ++mi)
                #pragma unroll
                for (int j = 0; j < 8; ++j)
                    st[mi][j] = __builtin_amdgcn_mfma_f32_16x16x32_bf16(
                        ak[j], bq[mi][1], st[mi][j], 0, 0, 0);
        }

        // ---- prefetch V frags (A-operand of PV): latency hides under softmax
        short8 av[4][4];    // [kvc][dj]: row=d=dj*16+l15, k=kv=kvc*32+l4*8+e
        #pragma unroll
        for (int kvc = 0; kvc < 4; ++kvc)
            #pragma unroll
            for (int dj = 0; dj < 4; ++dj)
                av[kvc][dj] = *(const short8*)&vb[(size_t)(dj * 16) * 2048
                                                  + kv0 + kvc * 32];

        // ---- in-lane online softmax (exp2 domain) ----
        float corr[2];
        #pragma unroll
        for (int mi = 0; mi < 2; ++mi) {
            float tm[8];
            #pragma unroll
            for (int j = 0; j < 8; ++j)
                tm[j] = fmaxf(fmaxf(st[mi][j][0], st[mi][j][1]),
                              fmaxf(st[mi][j][2], st[mi][j][3]));
            #pragma unroll
            for (int j = 0; j < 4; ++j) tm[j] = fmaxf(tm[j], tm[j + 4]);
            float mx = fmaxf(fmaxf(tm[0], tm[1]), fmaxf(tm[2], tm[3]));
            mx = fmaxf(mx, __shfl_xor(mx, 16));
            mx = fmaxf(mx, __shfl_xor(mx, 32));
            const float mnew = fmaxf(m_run[mi], mx);
            corr[mi] = exp2f(m_run[mi] - mnew);
            m_run[mi] = mnew;
            float ts[8];
            #pragma unroll
            for (int j = 0; j < 8; ++j) {
                float p0 = exp2f(st[mi][j][0] - mnew);
                float p1 = exp2f(st[mi][j][1] - mnew);
                float p2 = exp2f(st[mi][j][2] - mnew);
                float p3 = exp2f(st[mi][j][3] - mnew);
                st[mi][j][0] = p0; st[mi][j][1] = p1;
                st[mi][j][2] = p2; st[mi][j][3] = p3;
                ts[j] = (p0 + p1) + (p2 + p3);
            }
            #pragma unroll
            for (int j = 0; j < 4; ++j) ts[j] += ts[j + 4];
            float ls = (ts[0] + ts[1]) + (ts[2] + ts[3]);
            ls += __shfl_xor(ls, 16);
            ls += __shfl_xor(ls, 32);
            l_run[mi] = l_run[mi] * corr[mi] + ls;
            #pragma unroll
            for (int dj = 0; dj < 4; ++dj) acc[mi][dj] *= corr[mi];
        }

        // ---- P^T -> LDS as P[q][kv] (b64 writes, 4 consecutive kv) ----
        #pragma unroll
        for (int mi = 0; mi < 2; ++mi)
            #pragma unroll
            for (int j = 0; j < 8; ++j) {
                uint2v w;
                w.x = cvt_pk_bf16(st[mi][j][0], st[mi][j][1]);
                w.y = cvt_pk_bf16(st[mi][j][2], st[mi][j][3]);
                *(uint2v*)&P[wave][mi * 16 + l15][j * 16 + l4 * 4] = w;
            }

        // ---- O^T += V^T P^T ----
        #pragma unroll
        for (int kvc = 0; kvc < 4; ++kvc) {
            short8 pb[2];   // B-frag of P^T: col=q=l15, k=kv=kvc*32+l4*8+e
            #pragma unroll
            for (int mi = 0; mi < 2; ++mi)
                pb[mi] = *(const short8*)&P[wave][mi * 16 + l15][kvc * 32 + l4 * 8];
            #pragma unroll
            for (int mi = 0; mi < 2; ++mi)
                #pragma unroll
                for (int dj = 0; dj < 4; ++dj)
                    acc[mi][dj] = __builtin_amdgcn_mfma_f32_16x16x32_bf16(
                        av[kvc][dj], pb[mi], acc[mi][dj], 0, 0, 0);
        }
    }

    // ---- epilogue: divide by l (lane-local), 8B vector stores ----
    #pragma unroll
    for (int mi = 0; mi < 2; ++mi) {
        const float inv = 1.0f / l_run[mi];
        const int t = q0 + mi * 16 + l15;
        #pragma unroll
        for (int dj = 0; dj < 4; ++dj) {
            uint2v w;
            w.x = cvt_pk_bf16(acc[mi][dj][0] * inv, acc[mi][dj][1] * inv);
            w.y = cvt_pk_bf16(acc[mi][dj][2] * inv, acc[mi][dj][3] * inv);
            *(uint2v*)&op[((size_t)(b * 2048 + t)) * 1024
                          + h * 64 + dj * 16 + l4 * 4] = w;
        }
    }
}

// ---------------------------------------------------------------------------
extern "C" void kernel_launch(void* const* d_in, const int* in_sizes, int n_in,
                              void* d_out, int out_size, void* d_ws, size_t ws_size,
                              hipStream_t stream)
{
    const float* q  = (const float*)d_in[0];
    const float* k  = (const float*)d_in[1];
    const float* v  = (const float*)d_in[2];
    const float* wq = (const float*)d_in[3];
    const float* bq = (const float*)d_in[4];
    const float* wk = (const float*)d_in[5];
    const float* bk = (const float*)d_in[6];
    const float* wv = (const float*)d_in[7];
    const float* bv = (const float*)d_in[8];
    const float* wo = (const float*)d_in[9];
    const float* bo = (const float*)d_in[10];
    float* out = (float*)d_out;

    const int M = 4096, N = 1024, K = 1024;
    unsigned char* ws = (unsigned char*)d_ws;
    const size_t SX = (size_t)M * K * 2;        // 8 MB
    const size_t SW = (size_t)N * K * 2;        // 2 MB
    unsigned short* xq  = (unsigned short*)(ws);
    unsigned short* xk  = (unsigned short*)(ws + SX);
    unsigned short* xv  = (unsigned short*)(ws + 2 * SX);
    unsigned short* wqb = (unsigned short*)(ws + 3 * SX);
    unsigned short* wkb = (unsigned short*)(ws + 3 * SX + SW);
    unsigned short* wvb = (unsigned short*)(ws + 3 * SX + 2 * SW);
    unsigned short* wob = (unsigned short*)(ws + 3 * SX + 3 * SW);
    unsigned short* qp  = (unsigned short*)(ws + 3 * SX + 4 * SW);
    unsigned short* kp  = qp + (size_t)M * N;
    unsigned short* vt  = kp + (size_t)M * N;
    unsigned short* opb = vt + (size_t)M * N;

    pack3_bf16<<<dim3(4096, 3), 256, 0, stream>>>(q, k, v, xq, xk, xv,
                                                  M * K / 4);
    pack4_bf16<<<dim3(1024, 4), 256, 0, stream>>>(wq, wk, wv, wo,
                                                  wqb, wkb, wvb, wob, N * K / 4);

    gemm_qkv<<<dim3(8, 32, 3), 256, 0, stream>>>(xq, xk, xv, wqb, wkb, wvb,
                                                 bq, bk, bv, qp, kp, vt);

    attn_fwd<<<dim3(16, 32), 256, 0, stream>>>(qp, kp, vt, opb);

    gemm_out<<<dim3(8, 32), 256, 0, stream>>>(opb, wob, bo, out);
}

// Round 3
// 150.216 us; speedup vs baseline: 1.7197x; 1.4646x over previous
//
#include <hip/hip_runtime.h>
#include <math.h>

// ---------------------------------------------------------------------------
// MultiHeadAttention forward, MI355X/gfx950.  Round 3.
//   pack3/pack4: fp32 -> bf16
//   gemm_qkv (z=0,1,2): q' = (x@wq^T+bq)*0.125*log2e ; k' ; v -> vt [BH][64][T]
//   attn_fwd: 64-row q-tiles (1024 blocks, 4/CU), K/V cooperatively staged in
//             double-buffered XOR-swizzled LDS, swapped QK^T / swapped PV,
//             in-lane softmax (exp2 domain), P via swizzled per-wave LDS,
//             XCD-chunked block swizzle (each XCD's L2 holds 4 heads' KV)
//   gemm_out: out = attnout @ wo^T + bo (fp32)
// ---------------------------------------------------------------------------

typedef __attribute__((ext_vector_type(8))) short short8;     // 8 x bf16 frag
typedef __attribute__((ext_vector_type(4))) float f32x4;      // MFMA acc
typedef __attribute__((ext_vector_type(4))) float float4v;
typedef __attribute__((ext_vector_type(4))) unsigned short ushort4v;
typedef __attribute__((ext_vector_type(2))) unsigned int uint2v;

typedef __attribute__((address_space(3))) unsigned int lds_uint;
typedef __attribute__((address_space(1))) unsigned int glb_uint;

__device__ __forceinline__ void gload_lds16(const void* g, void* l) {
    __builtin_amdgcn_global_load_lds((glb_uint*)(unsigned long long)g,
                                     (lds_uint*)(unsigned int)(unsigned long long)l,
                                     16, 0, 0);
}

__device__ __forceinline__ unsigned short f32_bf16(float f) {
    union { float f; unsigned int u; } x; x.f = f;
    unsigned int r = x.u + 0x7fffu + ((x.u >> 16) & 1u);   // RNE
    return (unsigned short)(r >> 16);
}

__device__ __forceinline__ unsigned int cvt_pk_bf16(float lo, float hi) {
    unsigned int r;
    asm("v_cvt_pk_bf16_f32 %0, %1, %2" : "=v"(r) : "v"(lo), "v"(hi));
    return r;
}

// single-instruction exp2 (inputs <= 0; v_exp_f32 flushes underflow to 0)
__device__ __forceinline__ float exp2_fast(float x) {
    float r;
    asm("v_exp_f32 %0, %1" : "=v"(r) : "v"(x));
    return r;
}

// SCALE * log2(e): folded into Q projection so softmax runs in exp2 domain
#define QSCALE 0.18033688011112042f

// ---------------------------------------------------------------------------
__global__ void pack3_bf16(const float* __restrict__ a, const float* __restrict__ b,
                           const float* __restrict__ c,
                           unsigned short* __restrict__ oa, unsigned short* __restrict__ ob,
                           unsigned short* __restrict__ oc, int n4) {
    const int y = blockIdx.y;
    const float* in = (y == 0) ? a : (y == 1) ? b : c;
    unsigned short* out = (y == 0) ? oa : (y == 1) ? ob : oc;
    int i = blockIdx.x * blockDim.x + threadIdx.x;
    if (i < n4) {
        float4v v = ((const float4v*)in)[i];
        ushort4v o;
        o.x = f32_bf16(v.x); o.y = f32_bf16(v.y);
        o.z = f32_bf16(v.z); o.w = f32_bf16(v.w);
        ((ushort4v*)out)[i] = o;
    }
}

__global__ void pack4_bf16(const float* __restrict__ a, const float* __restrict__ b,
                           const float* __restrict__ c, const float* __restrict__ d,
                           unsigned short* __restrict__ oa, unsigned short* __restrict__ ob,
                           unsigned short* __restrict__ oc, unsigned short* __restrict__ od,
                           int n4) {
    const int y = blockIdx.y;
    const float* in = (y == 0) ? a : (y == 1) ? b : (y == 2) ? c : d;
    unsigned short* out = (y == 0) ? oa : (y == 1) ? ob : (y == 2) ? oc : od;
    int i = blockIdx.x * blockDim.x + threadIdx.x;
    if (i < n4) {
        float4v v = ((const float4v*)in)[i];
        ushort4v o;
        o.x = f32_bf16(v.x); o.y = f32_bf16(v.y);
        o.z = f32_bf16(v.z); o.w = f32_bf16(v.w);
        ((ushort4v*)out)[i] = o;
    }
}

// ---------------------------------------------------------------------------
// Batched QKV projection GEMM (unchanged from R2).
__global__ __launch_bounds__(256, 2) void gemm_qkv(
    const unsigned short* __restrict__ A0, const unsigned short* __restrict__ A1,
    const unsigned short* __restrict__ A2,
    const unsigned short* __restrict__ W0, const unsigned short* __restrict__ W1,
    const unsigned short* __restrict__ W2,
    const float* __restrict__ bs0, const float* __restrict__ bs1,
    const float* __restrict__ bs2,
    unsigned short* __restrict__ O0, unsigned short* __restrict__ O1,
    unsigned short* __restrict__ O2)
{
    const int z = blockIdx.z;
    const unsigned short* A = (z == 0) ? A0 : (z == 1) ? A1 : A2;
    const unsigned short* W = (z == 0) ? W0 : (z == 1) ? W1 : W2;
    const float* bias        = (z == 0) ? bs0 : (z == 1) ? bs1 : bs2;
    unsigned short* C        = (z == 0) ? O0 : (z == 1) ? O1 : O2;
    const float oscale = (z == 0) ? QSCALE : 1.0f;
    const int N = 1024, K = 1024;

    __shared__ unsigned short As[128 * 64];
    __shared__ unsigned short Bs[128 * 64];
    const int tid  = threadIdx.x;
    const int lane = tid & 63, wave = tid >> 6;
    const int l15 = lane & 15, l4 = lane >> 4;
    const int bm = blockIdx.y * 128, bn = blockIdx.x * 128;
    const int wr = wave >> 1, wc = wave & 1;

    f32x4 acc[4][4];
    #pragma unroll
    for (int i = 0; i < 4; ++i)
        #pragma unroll
        for (int j = 0; j < 4; ++j)
            #pragma unroll
            for (int e = 0; e < 4; ++e) acc[i][j][e] = 0.f;

    const int srow = lane >> 3;
    const int scol = (lane & 7) * 8;

    for (int k0 = 0; k0 < K; k0 += 64) {
        __syncthreads();
        #pragma unroll
        for (int i = 0; i < 4; ++i) {
            int c = wave * 4 + i;
            int row = c * 8 + srow;
            gload_lds16(A + (size_t)(bm + row) * K + k0 + scol, &As[c * 512]);
            gload_lds16(W + (size_t)(bn + row) * K + k0 + scol, &Bs[c * 512]);
        }
        __syncthreads();
        #pragma unroll
        for (int kk = 0; kk < 2; ++kk) {
            short8 af[4], bf[4];
            const int ko = kk * 32 + l4 * 8;
            #pragma unroll
            for (int i = 0; i < 4; ++i)
                af[i] = *(const short8*)&As[(wr * 64 + i * 16 + l15) * 64 + ko];
            #pragma unroll
            for (int j = 0; j < 4; ++j)
                bf[j] = *(const short8*)&Bs[(wc * 64 + j * 16 + l15) * 64 + ko];
            #pragma unroll
            for (int i = 0; i < 4; ++i)
                #pragma unroll
                for (int j = 0; j < 4; ++j)
                    acc[i][j] = __builtin_amdgcn_mfma_f32_16x16x32_bf16(
                        af[i], bf[j], acc[i][j], 0, 0, 0);
        }
    }

    #pragma unroll
    for (int j = 0; j < 4; ++j) {
        const int col = bn + wc * 64 + j * 16 + l15;
        const float bj = bias[col];
        #pragma unroll
        for (int i = 0; i < 4; ++i) {
            const int row0 = bm + wr * 64 + i * 16 + l4 * 4;
            #pragma unroll
            for (int r = 0; r < 4; ++r) {
                const int row = row0 + r;
                const float v = (acc[i][j][r] + bj) * oscale;
                if (z < 2) {
                    C[(size_t)row * N + col] = f32_bf16(v);
                } else {
                    const int b = row >> 11, t = row & 2047;
                    C[(((size_t)((b << 4) + (col >> 6)) * 64
                        + (col & 63)) << 11) + t] = f32_bf16(v);
                }
            }
        }
    }
}

// ---------------------------------------------------------------------------
// Output-projection GEMM (fp32 out, unchanged).
__global__ __launch_bounds__(256, 2) void gemm_out(
    const unsigned short* __restrict__ A,
    const unsigned short* __restrict__ W,
    const float* __restrict__ bias,
    float* __restrict__ C)
{
    const int N = 1024, K = 1024;
    __shared__ unsigned short As[128 * 64];
    __shared__ unsigned short Bs[128 * 64];
    const int tid  = threadIdx.x;
    const int lane = tid & 63, wave = tid >> 6;
    const int l15 = lane & 15, l4 = lane >> 4;
    const int bm = blockIdx.y * 128, bn = blockIdx.x * 128;
    const int wr = wave >> 1, wc = wave & 1;

    f32x4 acc[4][4];
    #pragma unroll
    for (int i = 0; i < 4; ++i)
        #pragma unroll
        for (int j = 0; j < 4; ++j)
            #pragma unroll
            for (int e = 0; e < 4; ++e) acc[i][j][e] = 0.f;

    const int srow = lane >> 3;
    const int scol = (lane & 7) * 8;

    for (int k0 = 0; k0 < K; k0 += 64) {
        __syncthreads();
        #pragma unroll
        for (int i = 0; i < 4; ++i) {
            int c = wave * 4 + i;
            int row = c * 8 + srow;
            gload_lds16(A + (size_t)(bm + row) * K + k0 + scol, &As[c * 512]);
            gload_lds16(W + (size_t)(bn + row) * K + k0 + scol, &Bs[c * 512]);
        }
        __syncthreads();
        #pragma unroll
        for (int kk = 0; kk < 2; ++kk) {
            short8 af[4], bf[4];
            const int ko = kk * 32 + l4 * 8;
            #pragma unroll
            for (int i = 0; i < 4; ++i)
                af[i] = *(const short8*)&As[(wr * 64 + i * 16 + l15) * 64 + ko];
            #pragma unroll
            for (int j = 0; j < 4; ++j)
                bf[j] = *(const short8*)&Bs[(wc * 64 + j * 16 + l15) * 64 + ko];
            #pragma unroll
            for (int i = 0; i < 4; ++i)
                #pragma unroll
                for (int j = 0; j < 4; ++j)
                    acc[i][j] = __builtin_amdgcn_mfma_f32_16x16x32_bf16(
                        af[i], bf[j], acc[i][j], 0, 0, 0);
        }
    }

    #pragma unroll
    for (int j = 0; j < 4; ++j) {
        const int col = bn + wc * 64 + j * 16 + l15;
        const float bj = bias[col];
        #pragma unroll
        for (int i = 0; i < 4; ++i) {
            const int row0 = bm + wr * 64 + i * 16 + l4 * 4;
            #pragma unroll
            for (int r = 0; r < 4; ++r)
                C[(size_t)(row0 + r) * N + col] = acc[i][j][r] + bj;
        }
    }
}

// ---------------------------------------------------------------------------
// Flash attention, R3.  Flat grid 1024 blocks, XCD-chunked: each XCD gets 4
// consecutive bh (2MB KV working set -> fits 4MB XCD L2).  Block: 4 waves,
// 64 q-rows (16/wave).  Per kv-tile (KVBLK=64): K/V staged cooperatively into
// double-buffered XOR-swizzled LDS via global_load_lds (2-phase pipeline);
// swapped QK^T (S^T) -> in-lane softmax -> P to swizzled per-wave LDS ->
// swapped PV (O^T).  LDS = 2*8K(K) + 2*8K(V) + 8K(P) = 40KB -> 4 blocks/CU.
__global__ __launch_bounds__(256, 4) void attn_fwd(
    const unsigned short* __restrict__ qp,
    const unsigned short* __restrict__ kp,
    const unsigned short* __restrict__ vt,
    unsigned short* __restrict__ op)
{
    __shared__ unsigned short Ks[2][64 * 64];   // [buf][kv][d]  swizzled
    __shared__ unsigned short Vs[2][64 * 64];   // [buf][d][kv]  swizzled
    __shared__ unsigned short P[4][16 * 64];    // [wave][q][kv] swizzled

    const int tid = threadIdx.x;
    const int lane = tid & 63, wave = tid >> 6;
    const int l15 = lane & 15, l4 = lane >> 4;
    const int swz = (l15 & 7) << 3;             // XOR mask in short units

    // XCD-chunked block swizzle: flat 1024 blocks, bijective (1024%8==0)
    const int flat = blockIdx.y * 32 + blockIdx.x;
    const int swzb = (flat & 7) * 128 + (flat >> 3);
    const int bx = swzb & 31;                   // q-tile index (64 rows)
    const int bh = swzb >> 5;                   // batch*head
    const int b = bh >> 4, h = bh & 15;
    const int q0 = bx * 64 + wave * 16;

    const size_t xbase = (size_t)b * 2048 * 1024 + h * 64;   // qp/kp
    const size_t vbase = (size_t)bh * 64 * 2048;             // vt

    // staging source addressing (pre-swizzled global col, m173 pattern)
    const int sr = lane >> 3;                   // row within 8-row chunk
    const int sc = ((lane & 7) ^ sr) * 8;       // swizzled col (shorts)

    // Q as B-operand frags: col=q(l15), k=d
    short8 bq[2];
    #pragma unroll
    for (int kk = 0; kk < 2; ++kk)
        bq[kk] = *(const short8*)&qp[xbase
            + (size_t)(q0 + l15) * 1024 + kk * 32 + l4 * 8];

    f32x4 acc[4];                   // O^T: [dj]; row=d_local, col=q=l15
    #pragma unroll
    for (int dj = 0; dj < 4; ++dj)
        #pragma unroll
        for (int e = 0; e < 4; ++e) acc[dj][e] = 0.f;

    float m_run = -1e30f, l_run = 0.f;          // per q-col (lane-local)

    // ---- prologue: stage tile 0 into buf 0 ----
    {
        const int c0 = wave * 2;
        #pragma unroll
        for (int i = 0; i < 2; ++i) {
            const int c = c0 + i;
            gload_lds16(kp + xbase + (size_t)(c * 8 + sr) * 1024 + sc,
                        &Ks[0][c * 512]);
            gload_lds16(vt + vbase + (size_t)(c * 8 + sr) * 2048 + sc,
                        &Vs[0][c * 512]);
        }
    }
    __syncthreads();

    const int NT = 2048 / 64;
    int buf = 0;
    for (int t = 0; t < NT; ++t) {
        const int kv0 = t * 64;
        // ---- stage next tile into buf^1 (latency hidden under compute) ----
        if (t + 1 < NT) {
            const int c0 = wave * 2;
            #pragma unroll
            for (int i = 0; i < 2; ++i) {
                const int c = c0 + i;
                gload_lds16(kp + xbase + (size_t)(kv0 + 64 + c * 8 + sr) * 1024 + sc,
                            &Ks[buf ^ 1][c * 512]);
                gload_lds16(vt + vbase + (size_t)(c * 8 + sr) * 2048 + kv0 + 64 + sc,
                            &Vs[buf ^ 1][c * 512]);
            }
        }

        // ---- S^T = K Q^T : A=K(row=kv,k=d), B=Q(col=q,k=d) ----
        f32x4 st[4];                // kv = j*16 + l4*4 + r ; q = l15
        {
            short8 ak[4];
            #pragma unroll
            for (int j = 0; j < 4; ++j)
                ak[j] = *(const short8*)&Ks[buf][(j * 16 + l15) * 64
                                                 + (((0 * 4 + l4) << 3) ^ swz)];
            const f32x4 z4 = {0.f, 0.f, 0.f, 0.f};
            #pragma unroll
            for (int j = 0; j < 4; ++j)
                st[j] = __builtin_amdgcn_mfma_f32_16x16x32_bf16(
                    ak[j], bq[0], z4, 0, 0, 0);
            #pragma unroll
            for (int j = 0; j < 4; ++j)
                ak[j] = *(const short8*)&Ks[buf][(j * 16 + l15) * 64
                                                 + (((1 * 4 + l4) << 3) ^ swz)];
            #pragma unroll
            for (int j = 0; j < 4; ++j)
                st[j] = __builtin_amdgcn_mfma_f32_16x16x32_bf16(
                    ak[j], bq[1], st[j], 0, 0, 0);
        }

        // ---- prefetch V frags from LDS (latency hides under softmax) ----
        short8 av[2][4];            // [kvc][dj]: row=d=dj*16+l15, k=kv
        #pragma unroll
        for (int kvc = 0; kvc < 2; ++kvc)
            #pragma unroll
            for (int dj = 0; dj < 4; ++dj)
                av[kvc][dj] = *(const short8*)&Vs[buf][(dj * 16 + l15) * 64
                                                 + (((kvc * 4 + l4) << 3) ^ swz)];

        // ---- in-lane online softmax (exp2 domain), q = l15 lane-local ----
        {
            float tm[4];
            #pragma unroll
            for (int j = 0; j < 4; ++j)
                tm[j] = fmaxf(fmaxf(st[j][0], st[j][1]),
                              fmaxf(st[j][2], st[j][3]));
            float mx = fmaxf(fmaxf(tm[0], tm[1]), fmaxf(tm[2], tm[3]));
            mx = fmaxf(mx, __shfl_xor(mx, 16));
            mx = fmaxf(mx, __shfl_xor(mx, 32));
            const float mnew = fmaxf(m_run, mx);
            const float corr = exp2_fast(m_run - mnew);
            m_run = mnew;
            float ts[4];
            #pragma unroll
            for (int j = 0; j < 4; ++j) {
                float p0 = exp2_fast(st[j][0] - mnew);
                float p1 = exp2_fast(st[j][1] - mnew);
                float p2 = exp2_fast(st[j][2] - mnew);
                float p3 = exp2_fast(st[j][3] - mnew);
                st[j][0] = p0; st[j][1] = p1; st[j][2] = p2; st[j][3] = p3;
                ts[j] = (p0 + p1) + (p2 + p3);
            }
            float ls = (ts[0] + ts[1]) + (ts[2] + ts[3]);
            ls += __shfl_xor(ls, 16);
            ls += __shfl_xor(ls, 32);
            l_run = l_run * corr + ls;
            #pragma unroll
            for (int dj = 0; dj < 4; ++dj) acc[dj] *= corr;
        }

        // ---- P^T -> swizzled per-wave LDS (b64 writes) ----
        #pragma unroll
        for (int j = 0; j < 4; ++j) {
            uint2v w;
            w.x = cvt_pk_bf16(st[j][0], st[j][1]);
            w.y = cvt_pk_bf16(st[j][2], st[j][3]);
            *(uint2v*)&P[wave][l15 * 64 + ((j * 16 + l4 * 4) ^ swz)] = w;
        }

        // ---- O^T += V^T P^T ----
        #pragma unroll
        for (int kvc = 0; kvc < 2; ++kvc) {
            short8 pb = *(const short8*)&P[wave][l15 * 64
                                                + (((kvc * 4 + l4) << 3) ^ swz)];
            #pragma unroll
            for (int dj = 0; dj < 4; ++dj)
                acc[dj] = __builtin_amdgcn_mfma_f32_16x16x32_bf16(
                    av[kvc][dj], pb, acc[dj], 0, 0, 0);
        }

        __syncthreads();            // drains vmcnt (prefetch done) + LDS reads
        buf ^= 1;
    }

    // ---- epilogue: divide by l (lane-local), 8B vector stores ----
    {
        const float inv = 1.0f / l_run;
        const int t = q0 + l15;
        #pragma unroll
        for (int dj = 0; dj < 4; ++dj) {
            uint2v w;
            w.x = cvt_pk_bf16(acc[dj][0] * inv, acc[dj][1] * inv);
            w.y = cvt_pk_bf16(acc[dj][2] * inv, acc[dj][3] * inv);
            *(uint2v*)&op[((size_t)(b * 2048 + t)) * 1024
                          + h * 64 + dj * 16 + l4 * 4] = w;
        }
    }
}

// ---------------------------------------------------------------------------
extern "C" void kernel_launch(void* const* d_in, const int* in_sizes, int n_in,
                              void* d_out, int out_size, void* d_ws, size_t ws_size,
                              hipStream_t stream)
{
    const float* q  = (const float*)d_in[0];
    const float* k  = (const float*)d_in[1];
    const float* v  = (const float*)d_in[2];
    const float* wq = (const float*)d_in[3];
    const float* bq = (const float*)d_in[4];
    const float* wk = (const float*)d_in[5];
    const float* bk = (const float*)d_in[6];
    const float* wv = (const float*)d_in[7];
    const float* bv = (const float*)d_in[8];
    const float* wo = (const float*)d_in[9];
    const float* bo = (const float*)d_in[10];
    float* out = (float*)d_out;

    const int M = 4096, N = 1024, K = 1024;
    unsigned char* ws = (unsigned char*)d_ws;
    const size_t SX = (size_t)M * K * 2;        // 8 MB
    const size_t SW = (size_t)N * K * 2;        // 2 MB
    unsigned short* xq  = (unsigned short*)(ws);
    unsigned short* xk  = (unsigned short*)(ws + SX);
    unsigned short* xv  = (unsigned short*)(ws + 2 * SX);
    unsigned short* wqb = (unsigned short*)(ws + 3 * SX);
    unsigned short* wkb = (unsigned short*)(ws + 3 * SX + SW);
    unsigned short* wvb = (unsigned short*)(ws + 3 * SX + 2 * SW);
    unsigned short* wob = (unsigned short*)(ws + 3 * SX + 3 * SW);
    unsigned short* qp  = (unsigned short*)(ws + 3 * SX + 4 * SW);
    unsigned short* kp  = qp + (size_t)M * N;
    unsigned short* vt  = kp + (size_t)M * N;
    unsigned short* opb = vt + (size_t)M * N;

    pack3_bf16<<<dim3(4096, 3), 256, 0, stream>>>(q, k, v, xq, xk, xv,
                                                  M * K / 4);
    pack4_bf16<<<dim3(1024, 4), 256, 0, stream>>>(wq, wk, wv, wo,
                                                  wqb, wkb, wvb, wob, N * K / 4);

    gemm_qkv<<<dim3(8, 32, 3), 256, 0, stream>>>(xq, xk, xv, wqb, wkb, wvb,
                                                 bq, bk, bv, qp, kp, vt);

    attn_fwd<<<dim3(32, 32), 256, 0, stream>>>(qp, kp, vt, opb);

    gemm_out<<<dim3(8, 32), 256, 0, stream>>>(opb, wob, bo, out);
}